// Round 4
// baseline (157.496 us; speedup 1.0000x reference)
//
#include <hip/hip_runtime.h>
#include <hip/hip_bf16.h>

typedef unsigned short u16;
typedef unsigned int u32;
typedef __attribute__((ext_vector_type(8))) short short8;
typedef __attribute__((ext_vector_type(4))) float f32x4;

#define MM 4096
#define NN 4096
#define KK 4096

#define BAR __builtin_amdgcn_s_barrier()
#define FENCE asm volatile("" ::: "memory")
#define WAITVM(n) asm volatile("s_waitcnt vmcnt(" #n ")" ::: "memory")

// LDS layout: Ab0 @0, Bb0 @16384, Ab1 @32768, Bb1 @49152 (u16 elements)
#define ABUF(sh, b) ((sh) + (b) * 32768)
#define BBUF(sh, b) ((sh) + 16384 + (b) * 32768)

__device__ __forceinline__ u16 f2bf(float f) {
  union { float f; u32 u; } v; v.f = f;
  u32 r = v.u + 0x7fffu + ((v.u >> 16) & 1u);
  return (u16)(r >> 16);
}

// ---- conversion passes: write PRE-SWIZZLED bf16 workspace ------------------
// Within each 64-elem (128B) K-window, dest chunk c' holds source chunk
// c' ^ (row&7). GEMM staging then reads the workspace fully linearly, and
// ldsfrag's XOR read recovers the original element order.
__global__ __launch_bounds__(256) void cvt_w_k(const int* __restrict__ w,
                                               u16* __restrict__ o) {
  int i = blockIdx.x * 256 + threadIdx.x;   // dest 16B chunk id
  int row = i >> 9;                          // 512 chunks per 4096-elem row
  int wi = i & 511;                          // chunk within row
  int src = (row << 12) + ((wi >> 3) << 6) + (((wi ^ row) & 7) << 3);
  const int4* w4 = (const int4*)(w + src);
  int4 a = w4[0], b = w4[1];
  short8 r;
  r[0] = (short)f2bf((float)a.x); r[1] = (short)f2bf((float)a.y);
  r[2] = (short)f2bf((float)a.z); r[3] = (short)f2bf((float)a.w);
  r[4] = (short)f2bf((float)b.x); r[5] = (short)f2bf((float)b.y);
  r[6] = (short)f2bf((float)b.z); r[7] = (short)f2bf((float)b.w);
  *(short8*)(o + (size_t)i * 8) = r;         // perfectly linear writes
}

__global__ __launch_bounds__(256) void cvt_a_k(const float* __restrict__ x,
                                               u16* __restrict__ o) {
  int i = blockIdx.x * 256 + threadIdx.x;
  int row = i >> 9;
  int wi = i & 511;
  int src = (row << 12) + ((wi >> 3) << 6) + (((wi ^ row) & 7) << 3);
  const float4* x4 = (const float4*)(x + src);
  float4 a = x4[0], b = x4[1];
  short8 r;
  r[0] = (short)f2bf(a.x); r[1] = (short)f2bf(a.y);
  r[2] = (short)f2bf(a.z); r[3] = (short)f2bf(a.w);
  r[4] = (short)f2bf(b.x); r[5] = (short)f2bf(b.y);
  r[6] = (short)f2bf(b.z); r[7] = (short)f2bf(b.w);
  *(short8*)(o + (size_t)i * 8) = r;
}

// ---- async global->LDS, width 16 ------------------------------------------
__device__ __forceinline__ void gload16(const u16* g, u16* l) {
  __builtin_amdgcn_global_load_lds(
      (const __attribute__((address_space(1))) void*)g,
      (__attribute__((address_space(3))) void*)l, 16, 0, 0);
}

// Stage one half-tile (128 rows x 64 cols bf16 = 16 KB) into LDS.
// Workspace is pre-swizzled, so both global reads and LDS writes are linear.
__device__ __forceinline__ void stage_half(const u16* __restrict__ gRowBase,
                                           int k0, u16* ldsHalf, int tid) {
#pragma unroll
  for (int i = 0; i < 2; ++i) {
    int p = i * 512 + tid;                 // 16B chunk, 0..1023
    int row = p >> 3;                      // 8 chunks per 64-elem row
    gload16(gRowBase + (size_t)row * KK + k0 + ((p & 7) << 3), ldsHalf + p * 8);
  }
}

// Swizzled ds_read of one 16B MFMA fragment: logical (row r, chunk q).
__device__ __forceinline__ short8 ldsfrag(const u16* base, int r, int q) {
  return *(const short8*)(base + r * 64 + (((q ^ r) & 7) << 3));
}

// ---- 256x256-tile 8-phase bf16 GEMM ---------------------------------------
template <int MODE>  // 0 = steady (t<=61), 1 = t==62, 2 = t==63
__device__ __forceinline__ void do_tile(
    int t, f32x4 (&acc)[8][4], const u16* Ag, const u16* Wg, u16* sh,
    int tid, int lr, int hi, int wr, int wc) {
  const int b = t & 1;
  const u16* Acur = ABUF(sh, b);
  const u16* Bcur = BBUF(sh, b);
  short8 bfr[4][2], afr[4][2];

  // ---- P1: read all B frags + A(mh0); stage (t+1) A1 -> buf b^1
#pragma unroll
  for (int n = 0; n < 4; ++n)
#pragma unroll
    for (int ks = 0; ks < 2; ++ks)
      bfr[n][ks] = ldsfrag(Bcur, wc * 64 + n * 16 + lr, ks * 4 + hi);
#pragma unroll
  for (int m = 0; m < 4; ++m)
#pragma unroll
    for (int ks = 0; ks < 2; ++ks)
      afr[m][ks] = ldsfrag(Acur, wr * 128 + m * 16 + lr, ks * 4 + hi);
  if (MODE <= 1) stage_half(Ag + 128 * KK, (t + 1) * 64, ABUF(sh, b ^ 1) + 8192, tid);
  FENCE; BAR;
  __builtin_amdgcn_s_setprio(1);
#pragma unroll
  for (int m = 0; m < 4; ++m)
#pragma unroll
    for (int n = 0; n < 2; ++n)
#pragma unroll
      for (int ks = 0; ks < 2; ++ks)
        acc[m][n] = __builtin_amdgcn_mfma_f32_16x16x32_bf16(
            afr[m][ks], bfr[n][ks], acc[m][n], 0, 0, 0);
  __builtin_amdgcn_s_setprio(0);
  FENCE; BAR;

  // ---- P2: no reads; stage (t+2) B0 -> buf b (B fully consumed in P1)
  if (MODE == 0) stage_half(Wg, (t + 2) * 64, BBUF(sh, b), tid);
  FENCE; BAR;
  __builtin_amdgcn_s_setprio(1);
#pragma unroll
  for (int m = 0; m < 4; ++m)
#pragma unroll
    for (int n = 0; n < 2; ++n)
#pragma unroll
      for (int ks = 0; ks < 2; ++ks)
        acc[m][2 + n] = __builtin_amdgcn_mfma_f32_16x16x32_bf16(
            afr[m][ks], bfr[2 + n][ks], acc[m][2 + n], 0, 0, 0);
  __builtin_amdgcn_s_setprio(0);
  FENCE; BAR;

  // ---- P3: read A(mh1) (overwrites afr); stage (t+2) B1 -> buf b
#pragma unroll
  for (int m = 0; m < 4; ++m)
#pragma unroll
    for (int ks = 0; ks < 2; ++ks)
      afr[m][ks] = ldsfrag(Acur, wr * 128 + 64 + m * 16 + lr, ks * 4 + hi);
  if (MODE == 0) stage_half(Wg + 128 * KK, (t + 2) * 64, BBUF(sh, b) + 8192, tid);
  FENCE; BAR;
  __builtin_amdgcn_s_setprio(1);
#pragma unroll
  for (int m = 0; m < 4; ++m)
#pragma unroll
    for (int n = 0; n < 2; ++n)
#pragma unroll
      for (int ks = 0; ks < 2; ++ks)
        acc[4 + m][n] = __builtin_amdgcn_mfma_f32_16x16x32_bf16(
            afr[m][ks], bfr[n][ks], acc[4 + m][n], 0, 0, 0);
  __builtin_amdgcn_s_setprio(0);
  FENCE; BAR;

  // ---- P4: stage (t+2) A0 -> buf b; once-per-K-tile counted vmcnt
  if (MODE == 0) {
    stage_half(Ag, (t + 2) * 64, ABUF(sh, b), tid);
    WAITVM(6);                 // t+1 fully landed; t+2 {B0,B1,A0} in flight
  } else if (MODE == 1) {
    WAITVM(0);                 // drain: t63 fully landed
  }
  FENCE; BAR;
  __builtin_amdgcn_s_setprio(1);
#pragma unroll
  for (int m = 0; m < 4; ++m)
#pragma unroll
    for (int n = 0; n < 2; ++n)
#pragma unroll
      for (int ks = 0; ks < 2; ++ks)
        acc[4 + m][2 + n] = __builtin_amdgcn_mfma_f32_16x16x32_bf16(
            afr[m][ks], bfr[2 + n][ks], acc[4 + m][2 + n], 0, 0, 0);
  __builtin_amdgcn_s_setprio(0);
  FENCE; BAR;
}

__global__ __launch_bounds__(512, 2) void gemm_k(const u16* __restrict__ A,
                                                 const u16* __restrict__ W,
                                                 const float* __restrict__ scales,
                                                 const float* __restrict__ bias,
                                                 float* __restrict__ out) {
  __shared__ u16 sh[4 * 16384];  // 128 KiB

  // T1: XCD-aware swizzle (nwg = 256, divisible by 8)
  const int cpx = gridDim.x >> 3;
  const int wg = (blockIdx.x & 7) * cpx + (blockIdx.x >> 3);
  const int bm = wg >> 4;
  const int bn = wg & 15;

  const int tid = threadIdx.x;
  const int lane = tid & 63;
  const int lr = lane & 15;
  const int hi = lane >> 4;
  const int wid = tid >> 6;
  const int wr = wid >> 2;  // 2 (M) x 4 (N) wave grid; wave tile 128x64
  const int wc = wid & 3;

  f32x4 acc[8][4] = {};

  const u16* Ag = A + (size_t)bm * 256 * KK;
  const u16* Wg = W + (size_t)bn * 256 * KK;

  // ---- prologue: tile0 all 4 halves + tile1 {B0,B1,A0}
  stage_half(Wg,             0, BBUF(sh, 0),        tid);
  stage_half(Wg + 128 * KK,  0, BBUF(sh, 0) + 8192, tid);
  stage_half(Ag,             0, ABUF(sh, 0),        tid);
  stage_half(Ag + 128 * KK,  0, ABUF(sh, 0) + 8192, tid);
  stage_half(Wg,            64, BBUF(sh, 1),        tid);
  stage_half(Wg + 128 * KK, 64, BBUF(sh, 1) + 8192, tid);
  stage_half(Ag,            64, ABUF(sh, 1),        tid);
  WAITVM(6);
  BAR;

  for (int t = 0; t < 62; ++t)
    do_tile<0>(t, acc, Ag, Wg, sh, tid, lr, hi, wr, wc);
  do_tile<1>(62, acc, Ag, Wg, sh, tid, lr, hi, wr, wc);
  do_tile<2>(63, acc, Ag, Wg, sh, tid, lr, hi, wr, wc);

  // ---- epilogue: coalesced fp32 stores via LDS transpose (2 rounds) -------
  // Round h: waves with wr==h dump their 128x64 acc tile into LDS slot wc
  // (XOR col^(hi<<4) => 2-way write conflicts only), then all 512 threads
  // store 128 rows x 256 cols with dwordx4 + fused scale/bias.
  float* shf = (float*)sh;                 // 32768 floats = 128 KiB
  const int colg = (tid & 63) * 4;         // 0..252, 16B aligned
  const int cslot = colg >> 6;             // which wave-slot holds these cols
  const int cin = colg & 63;
  const int gcol = bn * 256 + colg;
  const f32x4 s4 = *(const f32x4*)(scales + gcol);
  const f32x4 b4 = *(const f32x4*)(bias + gcol);
  const int rlo = tid >> 6;                // 0..7

#pragma unroll
  for (int h = 0; h < 2; ++h) {
    if (h) BAR;  // protect LDS from previous round's readers
    if (wr == h) {
      const int wbase = wc * 8192;
#pragma unroll
      for (int m = 0; m < 8; ++m)
#pragma unroll
        for (int n = 0; n < 4; ++n) {
          const int colw = (n * 16 + lr) ^ (hi << 4);
#pragma unroll
          for (int j = 0; j < 4; ++j)
            shf[wbase + (m * 16 + hi * 4 + j) * 64 + colw] = acc[m][n][j];
        }
    }
    FENCE; BAR;
#pragma unroll
    for (int it = 0; it < 16; ++it) {
      const int roww = it * 8 + rlo;       // 0..127 within this half
      const int X = ((roww >> 2) & 3) << 4;
      f32x4 v = *(const f32x4*)(shf + cslot * 8192 + roww * 64 + (cin ^ X));
      v = v * s4 + b4;
      *(f32x4*)(out + (size_t)(bm * 256 + h * 128 + roww) * NN + gcol) = v;
    }
  }
}

// ---- fallback (ws too small): correct but slow -----------------------------
__global__ __launch_bounds__(256) void fb_k(const float* __restrict__ A,
                                            const int* __restrict__ W,
                                            const float* __restrict__ scales,
                                            const float* __restrict__ bias,
                                            float* __restrict__ out) {
  __shared__ float Arow[KK];
  const int m = blockIdx.y;
  const int n0 = blockIdx.x * 256;
  const int tid = threadIdx.x;
  for (int k = tid; k < KK; k += 256) Arow[k] = A[(size_t)m * KK + k];
  __syncthreads();
  const int n = n0 + tid;
  float acc = 0.f;
  const int* wrp = W + (size_t)n * KK;
  for (int k = 0; k < KK; ++k) acc += Arow[k] * (float)wrp[k];
  out[(size_t)m * NN + n] = acc * scales[n] + bias[n];
}

extern "C" void kernel_launch(void* const* d_in, const int* in_sizes, int n_in,
                              void* d_out, int out_size, void* d_ws, size_t ws_size,
                              hipStream_t stream) {
  const float* input = (const float*)d_in[0];
  const int* w8 = (const int*)d_in[1];
  const float* scales = (const float*)d_in[2];
  const float* bias = (const float*)d_in[3];
  float* out = (float*)d_out;

  const size_t nelem = (size_t)NN * KK;
  const size_t need = 2 * nelem * sizeof(u16);

  if (ws_size >= need) {
    u16* Wbf = (u16*)d_ws;
    u16* Abf = Wbf + nelem;
    cvt_w_k<<<8192, 256, 0, stream>>>(w8, Wbf);
    cvt_a_k<<<8192, 256, 0, stream>>>(input, Abf);
    gemm_k<<<256, 512, 0, stream>>>(Abf, Wbf, scales, bias, out);
  } else {
    dim3 grid(NN / 256, MM);
    fb_k<<<grid, 256, 0, stream>>>(input, w8, scales, bias, out);
  }
}